// Round 11
// baseline (288.878 us; speedup 1.0000x reference)
//
#include <hip/hip_runtime.h>

// TriangleAttention, split design for MI355X (gfx950).
// Kernel A (tri_attn): per row r: LN -> Q/K/V/bias proj (f16 MFMA) -> masked
//   softmax+PV per head; normalized attention output written to workspace
//   as f16 [r][h][q][d] via coalesced stores. No O-proj, no att registers.
// Kernel B (oproj): out = (att . Wo^T + bo) * query-mask. Pure streaming
//   GEMM, 2048 small WGs, no LDS/barriers.
// r8 post-mortem: fused kernel spilled ~300 MB scratch (VGPR capped at 64).
// Split + amdgpu_waves_per_eu(4,4) keeps the hot kernel's live set <= 128.

#define SS 256
#define CC 128

typedef _Float16 f16;
typedef _Float16 f16x8 __attribute__((ext_vector_type(8)));
typedef _Float16 f16x4 __attribute__((ext_vector_type(4)));
typedef float f32x4 __attribute__((ext_vector_type(4)));

#define LOG2E 1.44269504088896340736f
#define SCALE2 (1.44269504088896340736f * 0.17677669529663688110f)  // log2e/sqrt(32)

// workspace layout (bytes): [0,135168) weights f16; att at 262144
#define ATT_OFF 262144

// LDS map kernel A: 77824 B -> 2 WG/CU
#define ZS_BASE 0       // 8 x 4KB per-wave scratch (LN / Q-stage / att-stage)
#define KB_BASE 32768   // per-head K  [256 key][32 d] f16, swz
#define VT_BASE 49152   // per-head V^T [32 d][256 key] f16, swz
#define PB_BASE 65536   // 4 x 2KB wave-pair P repack [16 q][64 kk] f16, swz
#define BS_BASE 73728   // bias' [4][256] f32 (mask & log2e folded)
#define SMEM_BYTES 77824

// [16 rows][128 c] f16, row stride 256B; XOR bits 4-6 < 256 OK
__device__ __forceinline__ int zs_addr(int base, int row, int c) {
  return base + (row << 8) + (((c << 1)) ^ ((row & 7) << 4));
}
// [32 q][32 d] f16, row stride 64B; XOR bits 4-5 < 64 OK
__device__ __forceinline__ int q_addr(int base, int q, int d) {
  return base + (q << 6) + ((d << 1) ^ ((q & 3) << 4));
}
// K [256 key][32 d] f16, row stride 64B; XOR bits 4-5 < 64 OK
__device__ __forceinline__ int k_addr(int key, int d) {
  return KB_BASE + (key << 6) + ((d << 1) ^ ((key & 3) << 4));
}
// V^T [32 d][256 key] f16, row stride 512B; XOR bits 4-6 < 512 OK
__device__ __forceinline__ int vt_addr(int d, int key) {
  return VT_BASE + (d << 9) + ((key << 1) ^ ((d & 7) << 4));
}
// P [16 q][64 kk] f16, row stride 128B; XOR bits 4-6 < 128 -> bijective
__device__ __forceinline__ int pb_addr(int base, int q, int kk) {
  return base + (q << 7) + ((kk << 1) ^ ((q & 7) << 4));
}

__global__ void prep_weights(const float* __restrict__ wq, const float* __restrict__ wk,
                             const float* __restrict__ wv, const float* __restrict__ wo,
                             const float* __restrict__ wb, f16* __restrict__ ws) {
  int i = blockIdx.x * 256 + threadIdx.x;
  if (i < 16384)        ws[i] = (f16)wq[i];
  else if (i < 32768)   ws[i] = (f16)wk[i - 16384];
  else if (i < 49152)   ws[i] = (f16)wv[i - 32768];
  else if (i < 65536)   ws[i] = (f16)wo[i - 49152];
  else if (i < 67584) { // Wb padded [16][128], rows 4..15 zero
    int j = i - 65536, row = j >> 7, col = j & 127;
    ws[i] = (row < 4) ? (f16)wb[row * 128 + col] : (f16)0.f;
  }
}

// ---- mask dtype sniff helper (verified r4): bool(1B)/int32/float32 --------
__device__ __forceinline__ bool sniff_mask4B(const unsigned int* pm32, int lane) {
  int notI32 = 0, notF32 = 0, f32seen = 0;
  for (int i = lane; i < 256; i += 64) {
    unsigned int w = pm32[i];
    if (w > 1u) notI32 = 1;
    if (w != 0u && w != 0x3F800000u) notF32 = 1;
    if (w == 0x3F800000u) f32seen = 1;
  }
  bool isI32 = (__ballot(notI32) == 0ULL);
  bool isF32 = !isI32 && (__ballot(notF32) == 0ULL) && (__ballot(f32seen) != 0ULL);
  return isI32 || isF32;
}

__global__ __launch_bounds__(512)
__attribute__((amdgpu_waves_per_eu(4, 4)))
void tri_attn(
    const float* __restrict__ z, const unsigned char* __restrict__ pm,
    const float* __restrict__ lnw, const float* __restrict__ lnb,
    const float* __restrict__ bq, const float* __restrict__ bk,
    const float* __restrict__ bv,
    const f16* __restrict__ wsbase, f16* __restrict__ attg) {
  __shared__ __align__(16) char smem[SMEM_BYTES];
  const f16* wq  = wsbase;
  const f16* wk  = wsbase + 16384;
  const f16* wv  = wsbase + 32768;
  const f16* wbp = wsbase + 65536;

  const int r = blockIdx.x;
  const int tid = threadIdx.x;
  const int wid = tid >> 6;
  const int lane = tid & 63;
  const int g = lane >> 4, l15 = lane & 15;
  const int ZS0 = ZS_BASE + wid * 4096;
  const int PB0 = PB_BASE + (wid >> 1) * 2048;  // wave-pair slot
  const int KOFF = (wid & 1) * 32;              // key-half within slot

  const unsigned int* pm32 = reinterpret_cast<const unsigned int*>(pm);
  const bool mask4B = sniff_mask4B(pm32, lane);

  // ---------------- P1: LayerNorm in 2 chunks of 16 rows -> aZ frags -------
  f16x8 aZ[2][4];
  {
    const int c4 = (lane & 31) * 4;
    const int half = lane >> 5;
    float4 w4 = *reinterpret_cast<const float4*>(lnw + c4);
    float4 b4 = *reinterpret_cast<const float4*>(lnb + c4);
#pragma unroll
    for (int mt = 0; mt < 2; ++mt) {
#pragma unroll 2
      for (int i = 0; i < 8; ++i) {
        int rloc = i * 2 + half;
        int row = wid * 32 + mt * 16 + rloc;
        float4 v = *reinterpret_cast<const float4*>(z + ((size_t)r * SS + row) * CC + c4);
        float s1 = v.x + v.y + v.z + v.w;
        float s2 = v.x * v.x + v.y * v.y + v.z * v.z + v.w * v.w;
#pragma unroll
        for (int m = 1; m <= 16; m <<= 1) { s1 += __shfl_xor(s1, m); s2 += __shfl_xor(s2, m); }
        float mu = s1 * (1.0f / 128.0f);
        float var = s2 * (1.0f / 128.0f) - mu * mu;
        float rs = rsqrtf(var + 1e-5f);
        f16x4 hv;
        hv[0] = (f16)((v.x - mu) * rs * w4.x + b4.x);
        hv[1] = (f16)((v.y - mu) * rs * w4.y + b4.y);
        hv[2] = (f16)((v.z - mu) * rs * w4.z + b4.z);
        hv[3] = (f16)((v.w - mu) * rs * w4.w + b4.w);
        *reinterpret_cast<f16x4*>(smem + zs_addr(ZS0, rloc, c4)) = hv;
      }
      // wave-local write->read; LDS per-wave in-order + compiler lgkmcnt
#pragma unroll
      for (int kt = 0; kt < 4; ++kt)
        aZ[mt][kt] = *reinterpret_cast<const f16x8*>(
            smem + zs_addr(ZS0, l15, kt * 32 + g * 8));
    }
  }

  // ---------------- P2: bias' all 4 heads (keys = own rows) ----------------
  {
    f16x8 bfr[4];
#pragma unroll
    for (int kt = 0; kt < 4; ++kt)
      bfr[kt] = *reinterpret_cast<const f16x8*>(wbp + l15 * 128 + kt * 32 + g * 8);
#pragma unroll
    for (int mt = 0; mt < 2; ++mt) {
      f32x4 acc = {0.f, 0.f, 0.f, 0.f};
#pragma unroll
      for (int kt = 0; kt < 4; ++kt)
        acc = __builtin_amdgcn_mfma_f32_16x16x32_f16(aZ[mt][kt], bfr[kt], acc, 0, 0, 0);
      if (l15 < 4) {
#pragma unroll
        for (int p = 0; p < 4; ++p) {
          int key = wid * 32 + mt * 16 + g * 4 + p;
          size_t e = (size_t)r * SS + key;
          bool mv = mask4B ? (pm32[e] != 0u) : (pm[e] != 0);
          float bb = mv ? acc[p] * LOG2E : -60000.0f;
          *reinterpret_cast<float*>(smem + BS_BASE + l15 * 1024 + key * 4) = bb;
        }
      }
    }
  }

  // ---------------- Head loop (rolled; all reg arrays static-indexed) ------
  for (int h = 0; h < 4; ++h) {
    // Q-proj -> own ZS slice [32 q][32 d], then qreg A-frags (wave-local)
#pragma unroll
    for (int nt = 0; nt < 2; ++nt) {
      int dg = h * 32 + nt * 16 + l15;
      float bcol = bq[dg];
      f16x8 bfr[4];
#pragma unroll
      for (int kt = 0; kt < 4; ++kt)
        bfr[kt] = *reinterpret_cast<const f16x8*>(wq + dg * 128 + kt * 32 + g * 8);
#pragma unroll
      for (int mt = 0; mt < 2; ++mt) {
        f32x4 acc = {0.f, 0.f, 0.f, 0.f};
#pragma unroll
        for (int kt = 0; kt < 4; ++kt)
          acc = __builtin_amdgcn_mfma_f32_16x16x32_f16(aZ[mt][kt], bfr[kt], acc, 0, 0, 0);
#pragma unroll
        for (int p = 0; p < 4; ++p)
          *reinterpret_cast<f16*>(smem + q_addr(ZS0, mt * 16 + g * 4 + p, nt * 16 + l15)) =
              (f16)(acc[p] + bcol);
      }
    }
    f16x8 qreg[2];
#pragma unroll
    for (int mt = 0; mt < 2; ++mt)
      qreg[mt] = *reinterpret_cast<const f16x8*>(
          smem + q_addr(ZS0, mt * 16 + l15, g * 8));

    __syncthreads();  // all waves done reading prev head's KB/VT

    // K-proj -> KB, V-proj -> VT (keys = own rows)
#pragma unroll
    for (int nt = 0; nt < 2; ++nt) {
      int dg = h * 32 + nt * 16 + l15;
      float bcK = bk[dg], bcV = bv[dg];
      f16x8 bK[4], bV[4];
#pragma unroll
      for (int kt = 0; kt < 4; ++kt) {
        bK[kt] = *reinterpret_cast<const f16x8*>(wk + dg * 128 + kt * 32 + g * 8);
        bV[kt] = *reinterpret_cast<const f16x8*>(wv + dg * 128 + kt * 32 + g * 8);
      }
#pragma unroll
      for (int mt = 0; mt < 2; ++mt) {
        f32x4 aK = {0.f, 0.f, 0.f, 0.f}, aV = {0.f, 0.f, 0.f, 0.f};
#pragma unroll
        for (int kt = 0; kt < 4; ++kt) {
          aK = __builtin_amdgcn_mfma_f32_16x16x32_f16(aZ[mt][kt], bK[kt], aK, 0, 0, 0);
          aV = __builtin_amdgcn_mfma_f32_16x16x32_f16(aZ[mt][kt], bV[kt], aV, 0, 0, 0);
        }
        int key0 = wid * 32 + mt * 16 + g * 4;
#pragma unroll
        for (int p = 0; p < 4; ++p)
          *reinterpret_cast<f16*>(smem + k_addr(key0 + p, nt * 16 + l15)) = (f16)(aK[p] + bcK);
        f16x4 pk;
#pragma unroll
        for (int p = 0; p < 4; ++p) pk[p] = (f16)(aV[p] + bcV);
        *reinterpret_cast<f16x4*>(smem + vt_addr(nt * 16 + l15, key0)) = pk;
      }
    }
    __syncthreads();  // KB/VT (and BS for h=0) visible

    // attention: 32 own queries vs 256 keys, streamed per 32-key chunk
#pragma unroll
    for (int mt = 0; mt < 2; ++mt) {
      f32x4 oacc0 = {0.f, 0.f, 0.f, 0.f}, oacc1 = {0.f, 0.f, 0.f, 0.f};
      float Lp[4] = {0.f, 0.f, 0.f, 0.f};
      for (int kc = 0; kc < 8; ++kc) {
        f16x8 kf0 = *reinterpret_cast<const f16x8*>(smem + k_addr(kc * 32 + l15, g * 8));
        f16x8 kf1 = *reinterpret_cast<const f16x8*>(smem + k_addr(kc * 32 + 16 + l15, g * 8));
        f32x4 zero = {0.f, 0.f, 0.f, 0.f};
        f32x4 s0 = __builtin_amdgcn_mfma_f32_16x16x32_f16(qreg[mt], kf0, zero, 0, 0, 0);
        f32x4 s1 = __builtin_amdgcn_mfma_f32_16x16x32_f16(qreg[mt], kf1, zero, 0, 0, 0);
        float b0 = *reinterpret_cast<const float*>(
            smem + BS_BASE + h * 1024 + (kc * 32 + l15) * 4);
        float b1 = *reinterpret_cast<const float*>(
            smem + BS_BASE + h * 1024 + (kc * 32 + 16 + l15) * 4);
#pragma unroll
        for (int p = 0; p < 4; ++p) {
          float e0 = __builtin_amdgcn_exp2f(fmaf(s0[p], SCALE2, b0));
          float e1 = __builtin_amdgcn_exp2f(fmaf(s1[p], SCALE2, b1));
          Lp[p] += e0 + e1;
          *reinterpret_cast<f16*>(smem + pb_addr(PB0, g * 4 + p, KOFF + l15)) = (f16)e0;
          *reinterpret_cast<f16*>(smem + pb_addr(PB0, g * 4 + p, KOFF + 16 + l15)) = (f16)e1;
        }
        f16x8 pf = *reinterpret_cast<const f16x8*>(smem + pb_addr(PB0, l15, KOFF + g * 8));
        f16x8 vf0 = *reinterpret_cast<const f16x8*>(smem + vt_addr(l15, kc * 32 + g * 8));
        f16x8 vf1 = *reinterpret_cast<const f16x8*>(smem + vt_addr(16 + l15, kc * 32 + g * 8));
        oacc0 = __builtin_amdgcn_mfma_f32_16x16x32_f16(pf, vf0, oacc0, 0, 0, 0);
        oacc1 = __builtin_amdgcn_mfma_f32_16x16x32_f16(pf, vf1, oacc1, 0, 0, 0);
      }
#pragma unroll
      for (int m = 1; m <= 8; m <<= 1)
#pragma unroll
        for (int p = 0; p < 4; ++p) Lp[p] += __shfl_xor(Lp[p], m);

      // normalized att -> ZS stage (wave-local) -> coalesced 16B global store
#pragma unroll
      for (int p = 0; p < 4; ++p) {
        float lr = 1.0f / fmaxf(Lp[p], 1e-20f);
        *reinterpret_cast<f16*>(smem + q_addr(ZS0, g * 4 + p, l15)) =
            (f16)(oacc0[p] * lr);
        *reinterpret_cast<f16*>(smem + q_addr(ZS0, g * 4 + p, 16 + l15)) =
            (f16)(oacc1[p] * lr);
      }
      {
        int e = lane * 8;            // element in [0,512): 16 q x 32 d
        int qloc = e >> 5, dd = e & 31;
        f16x8 v = *reinterpret_cast<const f16x8*>(smem + q_addr(ZS0, qloc, dd));
        size_t gq = (size_t)(((r * 4 + h) * 256) + wid * 32 + mt * 16 + qloc);
        *reinterpret_cast<f16x8*>(attg + gq * 32 + dd) = v;
      }
    }
  }
}

__global__ __launch_bounds__(256) void oproj(
    const f16* __restrict__ attg, const f16* __restrict__ wo,
    const unsigned char* __restrict__ pm, const float* __restrict__ bo,
    float* __restrict__ out) {
  const int r = blockIdx.x >> 2;
  const int q0 = (blockIdx.x & 3) * 64 + (threadIdx.x >> 6) * 16;  // wave's 16 q
  const int lane = threadIdx.x & 63;
  const int g = lane >> 4, l15 = lane & 15;

  const unsigned int* pm32 = reinterpret_cast<const unsigned int*>(pm);
  const bool mask4B = sniff_mask4B(pm32, lane);

  // A-frags: 16 q x 128 c, c = head kt * 32 + d
  f16x8 a[4];
#pragma unroll
  for (int kt = 0; kt < 4; ++kt)
    a[kt] = *reinterpret_cast<const f16x8*>(
        attg + ((size_t)((r * 4 + kt) * 256 + q0 + l15)) * 32 + g * 8);

  float qm[4];
#pragma unroll
  for (int p = 0; p < 4; ++p) {
    size_t e = (size_t)r * SS + q0 + g * 4 + p;
    qm[p] = (mask4B ? (pm32[e] != 0u) : (pm[e] != 0)) ? 1.0f : 0.0f;
  }

#pragma unroll
  for (int nt = 0; nt < 8; ++nt) {
    f32x4 acc = {0.f, 0.f, 0.f, 0.f};
#pragma unroll
    for (int kt = 0; kt < 4; ++kt) {
      f16x8 b = *reinterpret_cast<const f16x8*>(
          wo + (nt * 16 + l15) * 128 + kt * 32 + g * 8);
      acc = __builtin_amdgcn_mfma_f32_16x16x32_f16(a[kt], b, acc, 0, 0, 0);
    }
    float bc = bo[nt * 16 + l15];
#pragma unroll
    for (int p = 0; p < 4; ++p) {
      int q = q0 + g * 4 + p;
      out[((size_t)r * SS + q) * CC + nt * 16 + l15] = (acc[p] + bc) * qm[p];
    }
  }
}

extern "C" void kernel_launch(void* const* d_in, const int* in_sizes, int n_in,
                              void* d_out, int out_size, void* d_ws, size_t ws_size,
                              hipStream_t stream) {
  const float* z   = (const float*)d_in[0];
  const unsigned char* pmask = (const unsigned char*)d_in[1];  // dtype sniffed on device
  const float* lnw = (const float*)d_in[2];
  const float* lnb = (const float*)d_in[3];
  const float* Wq  = (const float*)d_in[4];
  const float* bq  = (const float*)d_in[5];
  const float* Wk  = (const float*)d_in[6];
  const float* bk  = (const float*)d_in[7];
  const float* Wv  = (const float*)d_in[8];
  const float* bv  = (const float*)d_in[9];
  const float* Wb  = (const float*)d_in[10];
  const float* Wo  = (const float*)d_in[11];
  const float* bo  = (const float*)d_in[12];
  f16* ws = (f16*)d_ws;
  f16* attg = (f16*)((char*)d_ws + ATT_OFF);  // needs ws_size >= ~34 MB

  prep_weights<<<264, 256, 0, stream>>>(Wq, Wk, Wv, Wo, Wb, ws);
  tri_attn<<<512, 512, 0, stream>>>(z, pmask, lnw, lnb, bq, bk, bv, ws, attg);
  oproj<<<2048, 256, 0, stream>>>(attg, ws + 49152, pmask, bo, (float*)d_out);
}